// Round 11
// baseline (281.125 us; speedup 1.0000x reference)
//
#include <hip/hip_runtime.h>
#include <hip/hip_bf16.h>

// Problem constants
#define B_   16
#define C_   256
#define T_   2048
#define PS   12
#define NNEG 15
#define OFFS 16
#define COPIES 16
#define NPRED 6225408           // sum_i (2032-i)*256
#define NLAB  389088

using bf16 = __hip_bfloat16;
typedef __attribute__((ext_vector_type(4))) float f32x4;
typedef __attribute__((ext_vector_type(8))) short bf16x8;

#define GLL(src, dst)                                                        \
    __builtin_amdgcn_global_load_lds(                                        \
        (const __attribute__((address_space(1))) void*)(src),                \
        (__attribute__((address_space(3))) void*)(dst), 16, 0, 0)

// ---------------------------------------------------------------- transpose z
// z[b][c][t] f32  ->  zT[b][t][c] bf16
__global__ __launch_bounds__(256) void transpose_z(const float* __restrict__ z,
                                                   bf16* __restrict__ zT) {
    __shared__ float tile[32][33];
    int t0 = blockIdx.x * 32, c0 = blockIdx.y * 32, b = blockIdx.z;
    int col = threadIdx.x & 31, r = threadIdx.x >> 5;
    for (int rr = 0; rr < 4; ++rr) {
        int row = r + rr * 8;
        tile[row][col] = z[(size_t)(b * C_ + c0 + row) * T_ + t0 + col];
    }
    __syncthreads();
    for (int rr = 0; rr < 4; ++rr) {
        int row = r + rr * 8;
        zT[(size_t)(b * T_ + t0 + row) * C_ + c0 + col] =
            __float2bfloat16(tile[col][row]);
    }
}

// ---------------------------------------------------------------- pack weight
// w[c][o][i] f32 -> wTb[j][c] bf16 with j = i*256 + o
__global__ __launch_bounds__(256) void pack_w(const float* __restrict__ w,
                                              bf16* __restrict__ wTb) {
    int gid = blockIdx.x * 256 + threadIdx.x;
    int j = gid >> 8, c = gid & 255;
    int o = j & 255, i = j >> 8;
    wTb[gid] = __float2bfloat16(w[(size_t)c * (C_ * PS) + o * PS + i]);
}

// ---------------------------------------------------------------- FUSED
// One block = (b, 32 consecutive s). 62KB LDS -> 2 blocks/CU (cross-block
// latency hiding). Loop cs = 0..7 over 32-channel slices:
//   GEMM M=48(43 used) x N=384(12i x 32o) x K=32; A from LDS, B(wTb) via
//   plain loads (L2). t8 gather issued pre-barrier (hides under epilogue;
//   raw s_barrier + lgkmcnt-only fences, no vmcnt drain). acc -> smZ bf16
//   (+bias, swizzled) -> predict 4 MFMA/wave accumulating oacc in regs.
__global__ __launch_bounds__(512, 4) void fused_kernel(
    const bf16* __restrict__ zT, const bf16* __restrict__ wTb,
    const float* __restrict__ bias, const int* __restrict__ neg,
    float* __restrict__ out) {
    __shared__ __align__(16) char smem[62464];
    char* smA = smem;                         // [48][512B]  A tile (swz)
    char* smZ = smem + 24576;                 // [48][768B]  zp slice (swz)
    float* smBias = (float*)(smem + 61440);   // 256 f32

    const int tid = threadIdx.x;
    const int wid = tid >> 6, lane = tid & 63;
    const int ln15 = lane & 15, kg = lane >> 4;

    int raw = blockIdx.x;                     // grid 1024 = 8 * 128 (bijective)
    int bid = (raw & 7) * 128 + (raw >> 3);
    const int b = bid >> 6, sblk = bid & 63;  // 64 s-blocks per b
    const int s0 = OFFS + sblk * 32;
    const int t_base = s0 - 27;

    if (tid < C_) smBias[tid] = bias[tid];

    // ---- A-tile stage: 48 rows, 3 GLL/wave, source-swizzled (g ^= row&7)
    {
        int g31 = lane & 31;
#pragma unroll
        for (int g = 0; g < 3; ++g) {
            int r2 = wid * 6 + g * 2;              // wave-uniform LDS base row
            int rt = r2 + (lane >> 5);             // per-lane source row
            int t = t_base + rt;
            t = t < 0 ? 0 : (t > T_ - 1 ? T_ - 1 : t);
            const char* src = (const char*)(zT + (size_t)(b * T_ + t) * C_) +
                              ((g31 ^ (rt & 7)) << 4);
            GLL(src, smA + r2 * 512);
        }
    }
    asm volatile("s_waitcnt vmcnt(0)" ::: "memory");
    __syncthreads();                          // A + bias published

    // ---- per-wave target rows (4 s per wave), cs-invariant, hoisted
    const int s_w = s0 + wid * 4;
    const int s_rd = s_w > T_ - 4 ? T_ - 4 : s_w;  // OOB-safe (masked stores)
    int srcrow[4];
    if (lane == 0) {
#pragma unroll
        for (int it = 0; it < 4; ++it) srcrow[it] = b * T_ + s_rd + it;
    } else if (lane < 16) {
        int4 n0 = *(const int4*)(neg + b * (NNEG * T_) + (lane - 1) * T_ + s_rd);
        srcrow[0] = n0.x; srcrow[1] = n0.y; srcrow[2] = n0.z; srcrow[3] = n0.w;
    } else {
#pragma unroll
        for (int it = 0; it < 4; ++it) srcrow[it] = 0;
    }
    const char* tp[4];                       // t8 base pointers (one shfl each)
#pragma unroll
    for (int it = 0; it < 4; ++it)
        tp[it] = (const char*)zT +
                 ((size_t)__shfl(srcrow[it], ln15) << 9) + (kg << 4);

    // ---- per-wave column metadata (N = 384 = 12i x 32o; wave owns 48 cols)
    const int wn = wid * 48;
    int wrow[3];                    // wTb row base: i*256 + o32
#pragma unroll
    for (int j = 0; j < 3; ++j) {
        int col = wn + j * 16 + ln15;
        wrow[j] = (col >> 5) * 256 + (col & 31);
    }
    int abase[3], a7[3];
#pragma unroll
    for (int m = 0; m < 3; ++m) {
        int r = m * 16 + ln15;
        abase[m] = r * 512;
        a7[m] = r & 7;
    }
    const int ii = ln15 < PS ? ln15 : 0;    // predict step (pad lanes dup 0)

    f32x4 oacc[4] = {};                     // out[s][n][i] partials, all cs

#pragma unroll 1
    for (int cs = 0; cs < 8; ++cs) {
        // -------- GEMM slice
        f32x4 acc[3][3] = {};
#pragma unroll
        for (int k = 0; k < 8; ++k) {
            bf16x8 bfr[3];
#pragma unroll
            for (int j = 0; j < 3; ++j)
                bfr[j] = *(const bf16x8*)((const char*)wTb +
                          (((size_t)(wrow[j] + cs * 32)) << 9) +
                          (k << 6) + (kg << 4));
            bf16x8 af[3];
#pragma unroll
            for (int m = 0; m < 3; ++m)
                af[m] = *(const bf16x8*)(smA + abase[m] +
                                         (((k * 4 + kg) ^ a7[m]) << 4));
#pragma unroll
            for (int m = 0; m < 3; ++m)
#pragma unroll
                for (int j = 0; j < 3; ++j)
                    acc[m][j] = __builtin_amdgcn_mfma_f32_16x16x32_bf16(
                        af[m], bfr[j], acc[m][j], 0, 0, 0);
        }

        // -------- issue t8 gather now; consumed after 2nd barrier
        bf16x8 t8[4];
#pragma unroll
        for (int it = 0; it < 4; ++it)
            t8[it] = *(const bf16x8*)(tp[it] + (cs << 6));

        // barrier 1: all waves' prior-cs smZ reads (+ this cs's af reads)
        // done before epilogue overwrites smZ. lgkm-only: t8 stays in flight.
        asm volatile("s_waitcnt lgkmcnt(0)" ::: "memory");
        __builtin_amdgcn_s_barrier();

        // -------- epilogue: acc(+bias) -> smZ bf16, swizzled granules
        {
            float bv0 = smBias[cs * 32 + ln15];
            float bv1 = smBias[cs * 32 + 16 + ln15];
#pragma unroll
            for (int m = 0; m < 3; ++m)
#pragma unroll
                for (int j = 0; j < 3; ++j) {
                    int col = wn + j * 16 + ln15;
                    float bvj = (((wid & 1) + j) & 1) ? bv1 : bv0;
#pragma unroll
                    for (int r = 0; r < 4; ++r) {
                        int row = m * 16 + kg * 4 + r;
                        int gz = (col >> 3) ^ (row & 7);
                        *(bf16*)(smZ + row * 768 + (gz << 4) +
                                 ((col & 7) << 1)) =
                            __float2bfloat16(acc[m][j][r] + bvj);
                    }
                }
        }

        // barrier 2: smZ published
        asm volatile("s_waitcnt lgkmcnt(0)" ::: "memory");
        __builtin_amdgcn_s_barrier();

        // -------- predict slice: zf from smZ + 4 MFMA
        {
            bf16x8 zf[4];
#pragma unroll
            for (int it = 0; it < 4; ++it) {
                int rowP = wid * 4 + it + 11 - ii;
                zf[it] = *(const bf16x8*)(smZ + rowP * 768 +
                          (((ii * 4 + kg) ^ (rowP & 7)) << 4));
            }
#pragma unroll
            for (int it = 0; it < 4; ++it)
                oacc[it] = __builtin_amdgcn_mfma_f32_16x16x32_bf16(
                    t8[it], zf[it], oacc[it], 0, 0, 0);
        }
    }

    // ---- final store (masked)
    if (ln15 < PS) {
        int i = ln15;
        int bi = 256 * ((T_ - OFFS) * i - (i * (i - 1)) / 2);
#pragma unroll
        for (int it = 0; it < 4; ++it) {
            int s = s_w + it;
            if (s < T_ && i <= s - OFFS) {
                int t = s - OFFS - i;
                *(f32x4*)(out + bi + (t * B_ + b) * COPIES + kg * 4) = oacc[it];
            }
        }
    }
}

// ---------------------------------------------------------------- launch
extern "C" void kernel_launch(void* const* d_in, const int* in_sizes, int n_in,
                              void* d_out, int out_size, void* d_ws, size_t ws_size,
                              hipStream_t stream) {
    const float* z    = (const float*)d_in[0];
    const float* w    = (const float*)d_in[1];
    const float* bias = (const float*)d_in[2];
    const int*   neg  = (const int*)d_in[3];
    float* out = (float*)d_out;

    char* ws = (char*)d_ws;
    bf16* zT  = (bf16*)ws;                                   // 16777216 B
    bf16* wTb = (bf16*)(ws + (size_t)B_ * T_ * C_ * sizeof(bf16));

    transpose_z<<<dim3(T_ / 32, C_ / 32, B_), 256, 0, stream>>>(z, zT);
    pack_w<<<(C_ * PS * C_) / 256, 256, 0, stream>>>(w, wTb);
    fused_kernel<<<1024, 512, 0, stream>>>(zT, wTb, bias, neg, out);
    hipMemsetAsync(out + NPRED, 0, NLAB * sizeof(float), stream);
}

// Round 12
// 150.749 us; speedup vs baseline: 1.8649x; 1.8649x over previous
//
#include <hip/hip_runtime.h>
#include <hip/hip_bf16.h>

// Problem constants
#define B_   16
#define C_   256
#define T_   2048
#define PS   12
#define NNEG 15
#define OFFS 16
#define COPIES 16

// Derived
#define M_GEMM (B_ * T_)        // 32768 rows (b,t)
#define N_GEMM (C_ * PS)        // 3072 cols (j = i*256 + o)
#define K_GEMM C_               // 256
#define NPRED 6225408           // sum_i (2032-i)*256
#define NLAB  389088

using bf16 = __hip_bfloat16;
typedef __attribute__((ext_vector_type(4))) float f32x4;
typedef __attribute__((ext_vector_type(8))) short bf16x8;

#define WAITVM(n) asm volatile("s_waitcnt vmcnt(" #n ")" ::: "memory")
#define GLL(src, dst)                                                        \
    __builtin_amdgcn_global_load_lds(                                        \
        (const __attribute__((address_space(1))) void*)(src),                \
        (__attribute__((address_space(3))) void*)(dst), 16, 0, 0)

// ---------------------------------------------------------------- transpose z
// z[b][c][t] f32  ->  zT[b][t][c] bf16
__global__ __launch_bounds__(256) void transpose_z(const float* __restrict__ z,
                                                   bf16* __restrict__ zT) {
    __shared__ float tile[32][33];
    int t0 = blockIdx.x * 32, c0 = blockIdx.y * 32, b = blockIdx.z;
    int col = threadIdx.x & 31, r = threadIdx.x >> 5;
    for (int rr = 0; rr < 4; ++rr) {
        int row = r + rr * 8;
        tile[row][col] = z[(size_t)(b * C_ + c0 + row) * T_ + t0 + col];
    }
    __syncthreads();
    for (int rr = 0; rr < 4; ++rr) {
        int row = r + rr * 8;
        zT[(size_t)(b * T_ + t0 + row) * C_ + c0 + col] =
            __float2bfloat16(tile[col][row]);
    }
}

// ---------------------------------------------------------------- pack weight
// w[c][o][i] f32 -> wTb[j][c] bf16 with j = i*256 + o
__global__ __launch_bounds__(256) void pack_w(const float* __restrict__ w,
                                              bf16* __restrict__ wTb) {
    int gid = blockIdx.x * 256 + threadIdx.x;
    int j = gid >> 8, c = gid & 255;
    int o = j & 255, i = j >> 8;
    wTb[gid] = __float2bfloat16(w[(size_t)c * (C_ * PS) + o * PS + i]);
}

// ---------------------------------------------------------------- z_pred GEMM
// 128x128 tile, 4 waves (2x2), BK=32, depth-3 counted-vmcnt LDS pipeline.
// R12: epilogue stores are NON-TEMPORAL (zp is a write-once stream consumed
// once by predict_kernel from L3/HBM; bypassing L2 avoids RFO/pollution).
#define EPAD 136

__global__ __launch_bounds__(256) void gemm_zpred(const bf16* __restrict__ zT,
                                                  const bf16* __restrict__ wTb,
                                                  const float* __restrict__ bias,
                                                  bf16* __restrict__ zp) {
    __shared__ __align__(16) char smem[49152];
    bf16* lE = (bf16*)smem;

    int bid = (blockIdx.x & 7) * 768 + (blockIdx.x >> 3);
    int bn = bid % (N_GEMM / 128);
    int bm = bid / (N_GEMM / 128);
    int tid = threadIdx.x;
    int wid = tid >> 6, lane = tid & 63;
    int ln15 = lane & 15, kg = lane >> 4;
    int wm = (wid & 1) * 64, wn = (wid >> 1) * 64;
    int row0 = bm * 128, col0 = bn * 128;
    int i_step = col0 >> 8;
    int o0 = col0 & 255;

    int gsw = ((lane & 3) ^ ((lane >> 3) & 3)) * 8;
    int srow = wid * 16 + (lane >> 2);
    const bf16* srcA = zT + (size_t)(row0 + srow) * 256 + gsw;
    const bf16* srcB = wTb + (size_t)(col0 + srow) * 256 + gsw;

    int offA[4], offB[4];
#pragma unroll
    for (int mi = 0; mi < 4; ++mi) {
        int r = wm + mi * 16 + ln15;
        offA[mi] = r * 64 + ((kg ^ ((r >> 1) & 3)) * 16);
    }
#pragma unroll
    for (int ni = 0; ni < 4; ++ni) {
        int c = wn + ni * 16 + ln15;
        offB[ni] = 8192 + c * 64 + ((kg ^ ((c >> 1) & 3)) * 16);
    }

    f32x4 acc[4][4] = {};

#define STAGE(t, slot_base)                                                  \
    {                                                                        \
        char* d = smem + (slot_base) + wid * 1024;                           \
        const bf16* sa = srcA + (t) * 32;                                    \
        const bf16* sb2 = srcB + (t) * 32;                                   \
        GLL(sa, d);                                                          \
        GLL(sa + 64 * 256, d + 4096);                                       \
        GLL(sb2, d + 8192);                                                  \
        GLL(sb2 + 64 * 256, d + 12288);                                     \
    }

#define TILE_BODY(slot_base, VMN)                                            \
    {                                                                        \
        WAITVM(VMN);                                                         \
        __builtin_amdgcn_s_barrier();                                        \
        const char* sb = smem + (slot_base);                                 \
        bf16x8 af[4], bfr[4];                                                \
        _Pragma("unroll") for (int mi = 0; mi < 4; ++mi)                     \
            af[mi] = *(const bf16x8*)(sb + offA[mi]);                        \
        _Pragma("unroll") for (int ni = 0; ni < 4; ++ni)                     \
            bfr[ni] = *(const bf16x8*)(sb + offB[ni]);                       \
        asm volatile("s_waitcnt lgkmcnt(0)" ::: "memory");                   \
        __builtin_amdgcn_sched_barrier(0);                                   \
        __builtin_amdgcn_s_barrier();                                        \
        __builtin_amdgcn_s_setprio(1);                                       \
        _Pragma("unroll") for (int mi = 0; mi < 4; ++mi)                     \
            _Pragma("unroll") for (int ni = 0; ni < 4; ++ni)                 \
                acc[mi][ni] = __builtin_amdgcn_mfma_f32_16x16x32_bf16(       \
                    af[mi], bfr[ni], acc[mi][ni], 0, 0, 0);                  \
        __builtin_amdgcn_s_setprio(0);                                       \
    }

    STAGE(0, 0);
    STAGE(1, 16384);
    STAGE(2, 32768);  TILE_BODY(0, 8);
    STAGE(3, 0);      TILE_BODY(16384, 8);
    STAGE(4, 16384);  TILE_BODY(32768, 8);
    STAGE(5, 32768);  TILE_BODY(0, 8);
    STAGE(6, 0);      TILE_BODY(16384, 8);
    STAGE(7, 16384);  TILE_BODY(32768, 8);
                      TILE_BODY(0, 4);
                      TILE_BODY(16384, 0);

    __syncthreads();

    float bv[4];
#pragma unroll
    for (int ni = 0; ni < 4; ++ni) bv[ni] = bias[o0 + wn + ni * 16 + ln15];

#pragma unroll
    for (int mi = 0; mi < 4; ++mi)
#pragma unroll
        for (int ni = 0; ni < 4; ++ni) {
            int col_e = wn + ni * 16 + ln15;
#pragma unroll
            for (int r = 0; r < 4; ++r) {
                int row_e = wm + mi * 16 + kg * 4 + r;
                lE[row_e * EPAD + col_e] = __float2bfloat16(acc[mi][ni][r] + bv[ni]);
            }
        }

    __syncthreads();

#pragma unroll
    for (int e = 0; e < 8; ++e) {
        int row_e = e * 16 + (tid >> 4);
        int grow = row0 + row_e;
        int b = grow >> 11, t = grow & (T_ - 1);
        int s = t + OFFS + i_step;
        if (s < T_) {
            bf16x8 v = *(const bf16x8*)&lE[row_e * EPAD + (tid & 15) * 8];
            __builtin_nontemporal_store(
                v, (bf16x8*)(zp + ((size_t)(b * T_ + s) * PS + i_step) * 256 +
                             o0 + (tid & 15) * 8));
        }
    }
#undef STAGE
#undef TILE_BODY
}

// ---------------------------------------------------------------- predictions
// One wave per (b,s) per iteration; 8 iters; 2 LDS slots (A 16x512B, zp
// 12x512B) staged via global_load_lds with COUNTED vmcnt. neg-row indices
// preloaded in the prologue; single f32x4 out-store -> exact vmcnt ledger.
__global__ __launch_bounds__(256) void predict_kernel(
    const bf16* __restrict__ zT, const bf16* __restrict__ zp,
    const int* __restrict__ neg, float* __restrict__ out) {
    __shared__ __align__(16) char psm[131072];
    int tid = threadIdx.x;
    int wid = tid >> 6, lane = tid & 63;
    int ln15 = lane & 15, kg = lane >> 4;
    char* my = psm + wid * 32768;           // wave-private: 2 slots x 16KB
    int base_gi = (blockIdx.x * 4 + wid) * 8;
    int b = base_gi / (T_ - OFFS);          // 8 | 2032: whole wave shares b
    int s_base = OFFS + base_gi % (T_ - OFFS);

    const char* zTb = (const char*)zT;
    const char* zpb = (const char*)zp;

    // ---- prologue: preload all neg rows for the wave's 8 (b,s) pairs
    int srcrow[8];
    if (lane == 0) {
#pragma unroll
        for (int it = 0; it < 8; ++it) srcrow[it] = b * T_ + s_base + it;
    } else if (lane < 16) {
        const int* np = neg + b * (NNEG * T_) + (lane - 1) * T_ + s_base;
        int4 n0 = *(const int4*)np;
        int4 n1 = *(const int4*)(np + 4);
        srcrow[0] = n0.x; srcrow[1] = n0.y; srcrow[2] = n0.z; srcrow[3] = n0.w;
        srcrow[4] = n1.x; srcrow[5] = n1.y; srcrow[6] = n1.z; srcrow[7] = n1.w;
    } else {
#pragma unroll
        for (int it = 0; it < 8; ++it) srcrow[it] = 0;
    }

    auto stage = [&](int it, int slot, int sr) {
        int s = s_base + it;
        char* dst = my + slot * 16384;
        int half = lane >> 5;
        int g31 = lane & 31;
#pragma unroll
        for (int j = 0; j < 8; ++j) {
            int r0 = __shfl(sr, 2 * j);
            int r1 = __shfl(sr, 2 * j + 1);
            int row = half ? r1 : r0;
            int n = 2 * j + half;
            GLL(zTb + (size_t)row * 512 + ((g31 ^ (n & 7)) << 4),
                dst + j * 1024);
        }
        size_t zoff = (size_t)(b * T_ + s) * (PS * 512);
#pragma unroll
        for (int j = 0; j < 6; ++j) {
            int i0 = 2 * j + half;
            GLL(zpb + zoff + i0 * 512 + ((g31 ^ (i0 & 7)) << 4),
                dst + 8192 + j * 1024);
        }
    };

    auto compute = [&](int it, int slot) {
        const char* sb = my + slot * 16384;
        int ii = ln15 < 12 ? ln15 : 0;      // dup col 0 for pad lanes (bcast)
        bf16x8 af[8], bfr[8];
#pragma unroll
        for (int kk = 0; kk < 8; ++kk) {
            int g = kk * 4 + kg;
            af[kk] = *(const bf16x8*)(sb + ln15 * 512 + ((g ^ (ln15 & 7)) << 4));
            bfr[kk] = *(const bf16x8*)(sb + 8192 + ii * 512 + ((g ^ (ii & 7)) << 4));
        }
        // frags secured in regs before this slot is restaged
        asm volatile("s_waitcnt lgkmcnt(0)" ::: "memory");
        __builtin_amdgcn_sched_barrier(0);
        if (it + 2 < 8) stage(it + 2, slot, srcrow[it + 2 < 8 ? it + 2 : 0]);

        f32x4 acc = {0.f, 0.f, 0.f, 0.f};
#pragma unroll
        for (int kk = 0; kk < 8; ++kk)
            acc = __builtin_amdgcn_mfma_f32_16x16x32_bf16(af[kk], bfr[kk], acc,
                                                          0, 0, 0);

        int s = s_base + it;
        int i = ln15;
        int imax = s - OFFS; if (imax > PS - 1) imax = PS - 1;
        if (i <= imax) {
            int t = s - OFFS - i;
            int base_i = 256 * ((T_ - OFFS) * i - (i * (i - 1)) / 2);
            float* o = out + base_i + (t * B_ + b) * COPIES + kg * 4;
            *(f32x4*)o = acc;               // single 16B store (1 VMEM op)
        }
    };

    stage(0, 0, srcrow[0]);
    stage(1, 1, srcrow[1]);

    // vmcnt ledger (FIFO): it0: 28 out -> WAIT(14) completes GLL(0).
    // steady: GLL(it)14 [+store] + GLL(it+1)14 + store -> WAIT(15) completes
    // exactly through GLL(it). drain it7: GLL(7)14 + store(6) -> WAIT(1).
    WAITVM(14); compute(0, 0);
    WAITVM(15); compute(1, 1);
    WAITVM(15); compute(2, 0);
    WAITVM(15); compute(3, 1);
    WAITVM(15); compute(4, 0);
    WAITVM(15); compute(5, 1);
    WAITVM(15); compute(6, 0);
    WAITVM(1);  compute(7, 1);
}

// ---------------------------------------------------------------- launch
extern "C" void kernel_launch(void* const* d_in, const int* in_sizes, int n_in,
                              void* d_out, int out_size, void* d_ws, size_t ws_size,
                              hipStream_t stream) {
    const float* z    = (const float*)d_in[0];
    const float* w    = (const float*)d_in[1];
    const float* bias = (const float*)d_in[2];
    const int*   neg  = (const int*)d_in[3];
    float* out = (float*)d_out;

    char* ws = (char*)d_ws;
    const size_t ZP_BYTES = (size_t)B_ * T_ * PS * 256 * sizeof(bf16);
    bf16* zp  = (bf16*)ws;
    bf16* zT  = (bf16*)(ws + ZP_BYTES + 8192);
    bf16* wTb = (bf16*)(ws + ZP_BYTES + 8192 + (size_t)M_GEMM * 256 * sizeof(bf16));

    transpose_z<<<dim3(T_ / 32, C_ / 32, B_), 256, 0, stream>>>(z, zT);
    pack_w<<<(N_GEMM * 256) / 256, 256, 0, stream>>>(w, wTb);
    gemm_zpred<<<(M_GEMM / 128) * (N_GEMM / 128), 256, 0, stream>>>(zT, wTb, bias, zp);
    predict_kernel<<<(B_ * (T_ - OFFS)) / 32, 256, 0, stream>>>(zT, zp, neg, out);
    hipMemsetAsync(out + NPRED, 0, NLAB * sizeof(float), stream);
}